// Round 4
// baseline (204.799 us; speedup 1.0000x reference)
//
#include <hip/hip_runtime.h>

typedef __attribute__((ext_vector_type(8))) short short8;
typedef __attribute__((ext_vector_type(4))) float f32x4;

#define KDIM 512

// ---- bf16 helpers (RNE) ----
__device__ __forceinline__ unsigned short f2bf(float x) {
    unsigned u = __float_as_uint(x);
    return (unsigned short)((u + 0x7FFFu + ((u >> 16) & 1u)) >> 16);
}
__device__ __forceinline__ float bf2f(unsigned short h) {
    return __uint_as_float(((unsigned)h) << 16);
}

// ---- async global->LDS 16B stage: per-lane g, wave-uniform LDS base ----
__device__ __forceinline__ void stage16(const void* g, void* l, int lane) {
    __builtin_amdgcn_global_load_lds(
        (const __attribute__((address_space(1))) unsigned int*)g,
        (__attribute__((address_space(3))) unsigned int*)l, 16, 0, 0);
}

// ===========================================================================
// Prep: swizzle weights to MFMA B-frag order (bf16).
// B-frag (16x16x32): lane l holds B[k0+(l>>4)*8+i][n0+(l&15)], i=0..7.
// Conv WC layout (16-k half-major, for half-granular staging):
//   idx = ((k>>4)*30 + (col>>4))*256 + ((k>>3)&1)*128 + (col&15)*8 + (k&7)
// Col map (480): f1@0(32,NP8) f2@32(64,NP7) f3@96(80,NP6) f4@176(80,NP5)
//                f5@256(80,NP4) f6@336(80,NP3) f7@416(64,NP2); col=FB+oc*NP+p
// ===========================================================================
__global__ void prep_kernel(const float* __restrict__ w1, const float* __restrict__ w2,
                            const float* __restrict__ w3, const float* __restrict__ w4,
                            const float* __restrict__ w5, const float* __restrict__ w6,
                            const float* __restrict__ w7, const float* __restrict__ hw1,
                            const float* __restrict__ hw2, const float* __restrict__ pw,
                            unsigned short* __restrict__ WC, unsigned short* __restrict__ W1s,
                            unsigned short* __restrict__ W2s, unsigned short* __restrict__ Ps) {
    int gid = blockIdx.x * 256 + threadIdx.x;
    if (gid < 245760) {                      // conv: 512*480
        int k = gid / 480, col = gid % 480;
        const float* wp; int cbnd, NP, C, W;
        if (col < 32)       { wp = w1; cbnd = 0;   NP = 8; C = 4;  W = 1; }
        else if (col < 96)  { wp = w2; cbnd = 32;  NP = 7; C = 8;  W = 2; }
        else if (col < 176) { wp = w3; cbnd = 96;  NP = 6; C = 12; W = 3; }
        else if (col < 256) { wp = w4; cbnd = 176; NP = 5; C = 16; W = 4; }
        else if (col < 336) { wp = w5; cbnd = 256; NP = 4; C = 20; W = 5; }
        else if (col < 416) { wp = w6; cbnd = 336; NP = 3; C = 24; W = 6; }
        else                { wp = w7; cbnd = 416; NP = 2; C = 28; W = 7; }
        int c2 = col - cbnd, oc = c2 / NP, p = c2 - oc * NP;
        int j = k >> 6, e = k & 63, dk = j - p;
        float v = 0.f;
        if (oc < C && dk >= 0 && dk < W) v = wp[(oc * 64 + e) * W + dk];
        WC[((k >> 4) * 30 + (col >> 4)) * 256 + ((k >> 3) & 1) * 128 + (col & 15) * 8 + (k & 7)] = f2bf(v);
    } else if (gid < 245760 + 57344) {       // highway: 2 x (128*224)
        int x = gid - 245760;
        const float* src = (x < 28672) ? hw1 : hw2;
        unsigned short* dst = (x < 28672) ? W1s : W2s;
        if (x >= 28672) x -= 28672;
        int k = x / 224, n = x % 224;
        float v = (k < 112) ? src[n * 112 + k] : 0.f;
        int q = k >> 5, kr = k & 31;
        dst[((q * 14 + (n >> 4)) * 64 + ((kr >> 3) * 16 + (n & 15))) * 8 + (kr & 7)] = f2bf(v);
    } else if (gid < 245760 + 57344 + 65536) { // proj: 128*512
        int x = gid - 303104;
        int k = x / 512, n = x % 512;
        float v = (k < 112) ? pw[n * 112 + k] : 0.f;
        int q = k >> 5, kr = k & 31;
        Ps[((q * 32 + (n >> 4)) * 64 + ((kr >> 3) * 16 + (n & 15))) * 8 + (kr & 7)] = f2bf(v);
    }
}

// ---- conv epilogue helpers ----
template <int T0, int T1>
__device__ __forceinline__ void dump_conv(float* Cb, const f32x4 (&acc)[4][8],
                                          int tbase, int ntile, int kq, int c0) {
#pragma unroll
    for (int j = 0; j < 8; ++j) {
        int t = tbase + j;
        if (j < ntile && t >= T0 && t < T1) {
#pragma unroll
            for (int rf = 0; rf < 4; ++rf)
#pragma unroll
                for (int r = 0; r < 4; ++r)
                    Cb[(rf * 16 + kq * 4 + r) * 161 + (t - T0) * 16 + c0] = acc[rf][j][r];
        }
    }
}

__device__ void reduce_phase(const float* Cb, unsigned short* ht, int tid,
                             int cA, int NPA, int choffA, int colbA, const float* cbA,
                             int cB, int NPB, int choffB, int colbB, const float* cbB) {
    int noc = cA + cB;
    for (int idx = tid; idx < 64 * noc; idx += 256) {
        int row = idx & 63, ocp = idx >> 6;
        bool isB = ocp >= cA;
        int oc = isB ? ocp - cA : ocp;
        int NP = isB ? NPB : NPA;
        int colb = isB ? colbB : colbA;
        int choff = isB ? choffB : choffA;
        const float* cb = isB ? cbB : cbA;
        const float* src = Cb + row * 161 + colb + oc * NP;
        float m = src[0];
        for (int k = 1; k < NP; ++k) m = fmaxf(m, src[k]);
        float v = fmaxf(m + cb[oc], 0.f);
        ht[row * 136 + choff + oc] = f2bf(v);
    }
}

// ===========================================================================
// Fused: conv GEMM (64x480, K=512) -> max/bias/relu -> hw1 -> hw2 -> proj.
// 512 blocks x 256 thr (4 waves). Conv: waves split COLUMNS (tiles
// {0-7,8-15,16-22,23-29}), each B-frag feeds 4 MFMAs (4 row-frags). A read
// from global fp32 (L1-cached), cvt in regs. h lives in LDS end-to-end.
// ===========================================================================
__global__ __launch_bounds__(256, 2) void fused_kernel(
        const float* __restrict__ feat, const unsigned short* __restrict__ WC,
        const float* cb0, const float* cb1, const float* cb2, const float* cb3,
        const float* cb4, const float* cb5, const float* cb6,
        const unsigned short* __restrict__ W1, const unsigned short* __restrict__ W2,
        const unsigned short* __restrict__ PW,
        const float* __restrict__ hb1, const float* __restrict__ hb2,
        const float* __restrict__ pb, float* __restrict__ out) {
    __shared__ __align__(16) char sm[65536];
    const int tid = threadIdx.x, lane = tid & 63, wave = tid >> 6;
    const int c0 = lane & 15, kq = lane >> 4;
    const int m0 = blockIdx.x * 64;
    const int tbase = wave * 8 - (wave == 3 ? 1 : 0);   // {0,8,16,23}
    const int ntile = (wave < 2) ? 8 : 7;
    f32x4 zero = {0.f, 0.f, 0.f, 0.f};

    // ---------------- conv GEMM ----------------
    f32x4 acc[4][8];
#pragma unroll
    for (int rf = 0; rf < 4; ++rf)
#pragma unroll
        for (int j = 0; j < 8; ++j) acc[rf][j] = zero;

    // prologue: stage B chunk 0 (30720 B), load A chunk 0
    for (int i = tid; i < 1920; i += 256)
        stage16(WC + i * 8, sm + (i - lane) * 16, lane);
    const float* fb = feat + (size_t)(m0 + c0) * KDIM + kq * 8;
    float4 ap[4][2];
#pragma unroll
    for (int rf = 0; rf < 4; ++rf) {
        ap[rf][0] = *(const float4*)(fb + rf * 16 * KDIM);
        ap[rf][1] = *(const float4*)(fb + rf * 16 * KDIM + 4);
    }
    const int bofs = (kq >> 1) * 15360 + (kq & 1) * 256 + c0 * 16;

#pragma unroll
    for (int q = 0; q < 16; ++q) {
        __syncthreads();               // chunk q staged (barrier drains vmcnt)
        if (q < 15) {                  // stage chunk q+1 into other buffer
            const unsigned short* src = WC + (q + 1) * 15360;
            char* dst = sm + ((q + 1) & 1) * 30720;
            for (int i = tid; i < 1920; i += 256)
                stage16(src + i * 8, dst + (i - lane) * 16, lane);
        }
        short8 aq[4];                  // cvt A(q) regs -> bf16 frags
#pragma unroll
        for (int rf = 0; rf < 4; ++rf) {
            float t[8];
            *(float4*)t = ap[rf][0]; *(float4*)(t + 4) = ap[rf][1];
            short8 v;
#pragma unroll
            for (int i = 0; i < 8; ++i) v[i] = (short)f2bf(t[i]);
            aq[rf] = v;
        }
        if (q < 15) {                  // prefetch A(q+1) into same regs (WAR ok)
#pragma unroll
            for (int rf = 0; rf < 4; ++rf) {
                ap[rf][0] = *(const float4*)(fb + rf * 16 * KDIM + (q + 1) * 32);
                ap[rf][1] = *(const float4*)(fb + rf * 16 * KDIM + (q + 1) * 32 + 4);
            }
        }
        const char* bb = sm + (q & 1) * 30720;
#pragma unroll
        for (int j = 0; j < 8; ++j) {
            if (j < ntile) {
                short8 b = *(const short8*)(bb + bofs + (tbase + j) * 512);
#pragma unroll
                for (int rf = 0; rf < 4; ++rf)
                    acc[rf][j] = __builtin_amdgcn_mfma_f32_16x16x32_bf16(aq[rf], b, acc[rf][j], 0, 0, 0);
            }
        }
    }

    // ---------------- conv epilogue: phased dump/reduce ----------------
    float* Cb = (float*)(sm + 17408);                 // 64 x 161 fp32 = 41216 B
    unsigned short* ht = (unsigned short*)sm;         // 64 rows, stride 136 bf16
    __syncthreads();                                  // bbuf dead
    for (int i = tid; i < 1024; i += 256)             // zero K-pad cols 112..127
        ht[(i >> 4) * 136 + 112 + (i & 15)] = 0;
    dump_conv<0, 6>(Cb, acc, tbase, ntile, kq, c0);
    __syncthreads();
    reduce_phase(Cb, ht, tid, 4, 8, 0, 0, cb0, 8, 7, 4, 32, cb1);
    __syncthreads();
    dump_conv<6, 16>(Cb, acc, tbase, ntile, kq, c0);
    __syncthreads();
    reduce_phase(Cb, ht, tid, 12, 6, 12, 0, cb2, 16, 5, 24, 80, cb3);
    __syncthreads();
    dump_conv<16, 26>(Cb, acc, tbase, ntile, kq, c0);
    __syncthreads();
    reduce_phase(Cb, ht, tid, 20, 4, 40, 0, cb4, 24, 3, 60, 80, cb5);
    __syncthreads();
    dump_conv<26, 30>(Cb, acc, tbase, ntile, kq, c0);
    __syncthreads();
    reduce_phase(Cb, ht, tid, 28, 2, 84, 0, cb6, 0, 1, 0, 0, cb6);
    __syncthreads();                                  // ht complete

    // ---------------- tail: hw1 -> hw2 -> proj ----------------
    char* wbuf = sm + 17408;                          // 32 KB stage region

    short8 a2[4];
#pragma unroll
    for (int q = 0; q < 4; ++q)
        a2[q] = *(const short8*)((const char*)ht + (wave * 16 + c0) * 272 + q * 64 + kq * 16);

    // GEMM2 (highway1), W1 in two 28 KB halves
    f32x4 acc2[14];
#pragma unroll
    for (int t = 0; t < 14; ++t) acc2[t] = zero;
    __syncthreads();                                  // a2 reads done (Cb region reuse)
    for (int i = tid; i < 1792; i += 256)
        stage16(W1 + i * 8, wbuf + (i - lane) * 16, lane);
    __syncthreads();
#pragma unroll
    for (int t = 0; t < 14; ++t)
#pragma unroll
        for (int q = 0; q < 2; ++q) {
            short8 b = *(const short8*)(wbuf + ((q * 14 + t) * 64 + lane) * 16);
            acc2[t] = __builtin_amdgcn_mfma_f32_16x16x32_bf16(a2[q], b, acc2[t], 0, 0, 0);
        }
    __syncthreads();
    for (int i = tid; i < 1792; i += 256)
        stage16(W1 + 14336 + i * 8, wbuf + (i - lane) * 16, lane);
    __syncthreads();
#pragma unroll
    for (int t = 0; t < 14; ++t)
#pragma unroll
        for (int q = 0; q < 2; ++q) {
            short8 b = *(const short8*)(wbuf + ((q * 14 + t) * 64 + lane) * 16);
            acc2[t] = __builtin_amdgcn_mfma_f32_16x16x32_bf16(a2[2 + q], b, acc2[t], 0, 0, 0);
        }

    // epilogue2: in-place highway on ht (thread RMWs its own element)
#pragma unroll
    for (int t = 0; t < 7; ++t) {
        float bp = hb1[t * 16 + c0], bg = hb1[112 + t * 16 + c0];
#pragma unroll
        for (int r = 0; r < 4; ++r) {
            int row = wave * 16 + kq * 4 + r;
            int col = t * 16 + c0;
            float px = acc2[t][r] + bp;
            float gt = acc2[t + 7][r] + bg;
            float g = 1.f / (1.f + __expf(-gt));
            float hres = bf2f(ht[row * 136 + col]);
            ht[row * 136 + col] = f2bf(g * hres + (1.f - g) * fmaxf(px, 0.f));
        }
    }

    short8 a3[4];
#pragma unroll
    for (int q = 0; q < 4; ++q)
        a3[q] = *(const short8*)((const char*)ht + (wave * 16 + c0) * 272 + q * 64 + kq * 16);

    // GEMM3 (highway2), W2 in two halves
    f32x4 acc3[14];
#pragma unroll
    for (int t = 0; t < 14; ++t) acc3[t] = zero;
    __syncthreads();
    for (int i = tid; i < 1792; i += 256)
        stage16(W2 + i * 8, wbuf + (i - lane) * 16, lane);
    __syncthreads();
#pragma unroll
    for (int t = 0; t < 14; ++t)
#pragma unroll
        for (int q = 0; q < 2; ++q) {
            short8 b = *(const short8*)(wbuf + ((q * 14 + t) * 64 + lane) * 16);
            acc3[t] = __builtin_amdgcn_mfma_f32_16x16x32_bf16(a3[q], b, acc3[t], 0, 0, 0);
        }
    __syncthreads();
    for (int i = tid; i < 1792; i += 256)
        stage16(W2 + 14336 + i * 8, wbuf + (i - lane) * 16, lane);
    __syncthreads();
#pragma unroll
    for (int t = 0; t < 14; ++t)
#pragma unroll
        for (int q = 0; q < 2; ++q) {
            short8 b = *(const short8*)(wbuf + ((q * 14 + t) * 64 + lane) * 16);
            acc3[t] = __builtin_amdgcn_mfma_f32_16x16x32_bf16(a3[2 + q], b, acc3[t], 0, 0, 0);
        }

    // epilogue3: in-place highway on ht
#pragma unroll
    for (int t = 0; t < 7; ++t) {
        float bp = hb2[t * 16 + c0], bg = hb2[112 + t * 16 + c0];
#pragma unroll
        for (int r = 0; r < 4; ++r) {
            int row = wave * 16 + kq * 4 + r;
            int col = t * 16 + c0;
            float px = acc3[t][r] + bp;
            float gt = acc3[t + 7][r] + bg;
            float g = 1.f / (1.f + __expf(-gt));
            float hres = bf2f(ht[row * 136 + col]);
            ht[row * 136 + col] = f2bf(g * hres + (1.f - g) * fmaxf(px, 0.f));
        }
    }

    short8 a4[4];
#pragma unroll
    for (int q = 0; q < 4; ++q)
        a4[q] = *(const short8*)((const char*)ht + (wave * 16 + c0) * 272 + q * 64 + kq * 16);

    // GEMM4 (proj): Ps streamed in 4 x 32 KB chunks
    f32x4 acc4[32];
#pragma unroll
    for (int t = 0; t < 32; ++t) acc4[t] = zero;
#pragma unroll
    for (int q = 0; q < 4; ++q) {
        __syncthreads();
        for (int i = tid; i < 2048; i += 256)
            stage16(PW + q * 16384 + i * 8, wbuf + (i - lane) * 16, lane);
        __syncthreads();
#pragma unroll
        for (int t = 0; t < 32; ++t) {
            short8 b = *(const short8*)(wbuf + (t * 64 + lane) * 16);
            acc4[t] = __builtin_amdgcn_mfma_f32_16x16x32_bf16(a4[q], b, acc4[t], 0, 0, 0);
        }
    }

    // epilogue4: +bias, coalesced store via LDS transpose (2 halves x 256 cols)
    float* ot = (float*)sm;
#pragma unroll
    for (int half = 0; half < 2; ++half) {
        __syncthreads();
#pragma unroll
        for (int t16 = 0; t16 < 16; ++t16) {
            int col = (half * 16 + t16) * 16 + c0;
            float b = pb[col];
#pragma unroll
            for (int r = 0; r < 4; ++r)
                ot[(wave * 16 + kq * 4 + r) * 256 + t16 * 16 + c0] = acc4[half * 16 + t16][r] + b;
        }
        __syncthreads();
        for (int i = tid; i < 4096; i += 256) {
            int row = i >> 6, c = i & 63;
            *(float4*)(out + (size_t)(m0 + row) * 512 + half * 256 + c * 4) = ((const float4*)ot)[i];
        }
    }
}

// ===========================================================================
extern "C" void kernel_launch(void* const* d_in, const int* in_sizes, int n_in,
                              void* d_out, int out_size, void* d_ws, size_t ws_size,
                              hipStream_t stream) {
    const float* feat = (const float*)d_in[0];
    const float* cw[7];
    const float* cb[7];
    for (int f = 0; f < 7; ++f) {
        cw[f] = (const float*)d_in[1 + 2 * f];
        cb[f] = (const float*)d_in[2 + 2 * f];
    }
    const float* hw_w1 = (const float*)d_in[15];
    const float* hw_b1 = (const float*)d_in[16];
    const float* hw_w2 = (const float*)d_in[17];
    const float* hw_b2 = (const float*)d_in[18];
    const float* pw    = (const float*)d_in[19];
    const float* pb    = (const float*)d_in[20];
    float* out = (float*)d_out;

    char* ws = (char*)d_ws;
    unsigned short* WC  = (unsigned short*)ws;                  // 491,520 B
    unsigned short* W1s = (unsigned short*)(ws + 491520);       //  57,344 B
    unsigned short* W2s = (unsigned short*)(ws + 548864);       //  57,344 B
    unsigned short* Ps  = (unsigned short*)(ws + 606208);       // 131,072 B

    prep_kernel<<<1440, 256, 0, stream>>>(cw[0], cw[1], cw[2], cw[3], cw[4], cw[5], cw[6],
                                          hw_w1, hw_w2, pw, WC, W1s, W2s, Ps);
    fused_kernel<<<512, 256, 0, stream>>>(feat, WC,
                                          cb[0], cb[1], cb[2], cb[3], cb[4], cb[5], cb[6],
                                          W1s, W2s, Ps, hw_b1, hw_b2, pb, out);
}